// Round 8
// baseline (375.581 us; speedup 1.0000x reference)
//
#include <hip/hip_runtime.h>
#include <hip/hip_bf16.h>
#include <stdint.h>

typedef __bf16 bf16;
typedef __bf16 bf16x4 __attribute__((ext_vector_type(4)));
typedef __bf16 bf16x8 __attribute__((ext_vector_type(8)));
typedef float floatx4 __attribute__((ext_vector_type(4)));
typedef float floatx16 __attribute__((ext_vector_type(16)));

#define B_SEQ 16
#define NLBL  5000
#define DLAT  1024
#define PDIM  1100
#define NROWS (B_SEQ * NLBL)   // 80000 = 625 * 128

// NOTE (R6 post-mortem): do NOT use the builtin's immediate-offset arg — it
// mis-addresses (absmax 3600). k0 must be baked into the global vaddr.
__device__ __forceinline__ void gload_lds16(const bf16* g, bf16* l) {
    __builtin_amdgcn_global_load_lds(
        (const __attribute__((address_space(1))) void*)g,
        (__attribute__((address_space(3))) void*)l, 16, 0, 0);
}

__device__ __forceinline__ bf16x8 cvt8(const float* s) {
    floatx4 a = *(const floatx4*)s;
    floatx4 b = *(const floatx4*)(s + 4);
    bf16x8 o;
    o[0] = (bf16)a.x; o[1] = (bf16)a.y; o[2] = (bf16)a.z; o[3] = (bf16)a.w;
    o[4] = (bf16)b.x; o[5] = (bf16)b.y; o[6] = (bf16)b.z; o[7] = (bf16)b.w;
    return o;
}

// ============ K1: prep ============
// [0,256)       M-GEMM: M[d,l] = sum_k W1[d,1024+k]*Wl[k,l]  (inline f32->bf16)
// [256,2756)    label f32->bf16
// [2756,3268)   W2 f32->bf16
// [3268,3524)   Pe[b,d] = seq[b,:].Wp[d,:]  (f32 exact)
// [3524,3837)   out init to b3
#define PSEG_M    256
#define PSEG_LAB  2756
#define PSEG_W2   3268
#define PSEG_PE   3524
#define PSEG_END  3837

__global__ __launch_bounds__(256)
void prep_kernel(const float* __restrict__ label, bf16* __restrict__ label_b,
                 const float* __restrict__ W2, bf16* __restrict__ W2_b,
                 const float* __restrict__ W1, const float* __restrict__ Wl,
                 bf16* __restrict__ M_bf,
                 const float* __restrict__ seq, const float* __restrict__ Wp,
                 float* __restrict__ Pe,
                 float* __restrict__ out, const float* __restrict__ b3) {
    __shared__ bf16 MAs[64 * 72];
    __shared__ bf16 MBs[64 * 72];
    const int blk = blockIdx.x;
    const int t = threadIdx.x;

    if (blk < PSEG_M) {                     // M-product, 64x64 tiles, 16x16 grid
        const int m0 = (blk >> 4) * 64;     // d rows
        const int n0g = (blk & 15) * 64;    // l cols
        const int wave = t >> 6, lane = t & 63;
        const int wm = (wave & 1) * 32, wn = (wave >> 1) * 32;
        const int lm = lane & 15, quad = lane >> 4;
        const int a_r = t >> 2, a_c = (t & 3) * 16;
        const int b_kr = t >> 4, b_l = (t & 15) * 4;
        floatx4 acc[2][2] = {};

        for (int k0 = 0; k0 < 1024; k0 += 64) {
            const float* ap = W1 + (size_t)(m0 + a_r) * 2048 + 1024 + k0 + a_c;
            *(bf16x8*)(MAs + a_r * 72 + a_c) = cvt8(ap);
            *(bf16x8*)(MAs + a_r * 72 + a_c + 8) = cvt8(ap + 8);
#pragma unroll
            for (int ps = 0; ps < 4; ++ps) {
                int kr = b_kr + ps * 16;
                floatx4 v = *(const floatx4*)(Wl + (size_t)(k0 + kr) * 1024 + n0g + b_l);
                MBs[(b_l + 0) * 72 + kr] = (bf16)v.x;
                MBs[(b_l + 1) * 72 + kr] = (bf16)v.y;
                MBs[(b_l + 2) * 72 + kr] = (bf16)v.z;
                MBs[(b_l + 3) * 72 + kr] = (bf16)v.w;
            }
            __syncthreads();
#pragma unroll
            for (int ks = 0; ks < 2; ++ks) {
                bf16x8 af[2], bg[2];
#pragma unroll
                for (int mi = 0; mi < 2; ++mi)
                    af[mi] = *(const bf16x8*)(MAs + (wm + mi * 16 + lm) * 72 + ks * 32 + quad * 8);
#pragma unroll
                for (int ni = 0; ni < 2; ++ni)
                    bg[ni] = *(const bf16x8*)(MBs + (wn + ni * 16 + lm) * 72 + ks * 32 + quad * 8);
#pragma unroll
                for (int mi = 0; mi < 2; ++mi)
#pragma unroll
                    for (int ni = 0; ni < 2; ++ni)
                        acc[mi][ni] = __builtin_amdgcn_mfma_f32_16x16x32_bf16(af[mi], bg[ni], acc[mi][ni], 0, 0, 0);
            }
            __syncthreads();
        }
#pragma unroll
        for (int mi = 0; mi < 2; ++mi)
#pragma unroll
            for (int r = 0; r < 4; ++r)
#pragma unroll
                for (int ni = 0; ni < 2; ++ni)
                    M_bf[(size_t)(m0 + wm + mi * 16 + quad * 4 + r) * 1024 + n0g + wn + ni * 16 + lm] =
                        (bf16)acc[mi][ni][r];
    } else if (blk < PSEG_LAB) {            // label convert
        int i = (blk - PSEG_M) * 256 + t;
        ((bf16x8*)label_b)[i] = cvt8(label + (size_t)i * 8);
    } else if (blk < PSEG_W2) {             // W2 convert
        int i = (blk - PSEG_LAB) * 256 + t;
        ((bf16x8*)W2_b)[i] = cvt8(W2 + (size_t)i * 8);
    } else if (blk < PSEG_PE) {             // Pe, wave per d
        int w = (blk - PSEG_W2) * 4 + (t >> 6);
        int l = t & 63;
        floatx4 wv[5];
#pragma unroll
        for (int k = 0; k < 5; ++k) {
            int g = l + 64 * k;
            wv[k] = (g < 275) ? *(const floatx4*)(Wp + (size_t)w * PDIM + g * 4)
                              : floatx4{0.f, 0.f, 0.f, 0.f};
        }
        for (int b = 0; b < B_SEQ; ++b) {
            float acc = 0.f;
#pragma unroll
            for (int k = 0; k < 5; ++k) {
                int g = l + 64 * k;
                if (g < 275) {
                    floatx4 sv = *(const floatx4*)(seq + (size_t)b * PDIM + g * 4);
                    acc += wv[k].x * sv.x + wv[k].y * sv.y + wv[k].z * sv.z + wv[k].w * sv.w;
                }
            }
#pragma unroll
            for (int off = 32; off; off >>= 1) acc += __shfl_xor(acc, off, 64);
            if (l == 0) Pe[b * DLAT + w] = acc;
        }
    } else {                                // out init
        int i = (blk - PSEG_PE) * 256 + t;
        if (i < NROWS) out[i] = b3[0];
    }
}

// ============ K2: hpb[b,o] = b1[o] + Pe[b,:].W1[o,0:1024]  (f32 exact) ============

__global__ __launch_bounds__(256)
void hpb_kernel(const float* __restrict__ Pe, const float* __restrict__ W1,
                const float* __restrict__ b1, float* __restrict__ hpb) {
    int w = blockIdx.x * 4 + (threadIdx.x >> 6);
    int l = threadIdx.x & 63;
    floatx4 wv[4];
#pragma unroll
    for (int k = 0; k < 4; ++k)
        wv[k] = *(const floatx4*)(W1 + (size_t)w * 2048 + (l + 64 * k) * 4);
    for (int b = 0; b < B_SEQ; ++b) {
        float acc = 0.f;
#pragma unroll
        for (int k = 0; k < 4; ++k) {
            floatx4 pv = *(const floatx4*)(Pe + (size_t)b * DLAT + (l + 64 * k) * 4);
            acc += wv[k].x * pv.x + wv[k].y * pv.y + wv[k].z * pv.z + wv[k].w * pv.w;
        }
#pragma unroll
        for (int off = 32; off; off >>= 1) acc += __shfl_xor(acc, off, 64);
        if (l == 0) hpb[b * DLAT + w] = acc + b1[w];
    }
}

// ============ K3: hl GEMM (label @ M.T) with coalesced h1 epilogue (r5 form) ============
// h1[(b*5000+n), d] = bf16(relu(hpb[b,d] + hl[n,d])) for all 16 b.

__global__ __launch_bounds__(256)
void hl_h1_kernel(const bf16* __restrict__ A, const bf16* __restrict__ Bt,
                  const float* __restrict__ hpb, bf16* __restrict__ h1) {
    __shared__ __align__(16) char smem[43008];
    bf16* As = (bf16*)smem;                 // 16 KB (K-loop)
    bf16* Bs = (bf16*)(smem + 16384);       // 16 KB (K-loop)
    bf16* Ls = (bf16*)smem;                 // 128*136*2 = 34816 B (epilogue)
    float* hpbs = (float*)(smem + 34816);   // 16*128*4 = 8192 B (epilogue)

    const int t = threadIdx.x;
    const int n0 = blockIdx.x * 128;        // d-tile (8)
    const int m0 = blockIdx.y * 128;        // n-tile (40, last partial)
    const int wave = t >> 6, lane = t & 63;
    const int wm = (wave & 1) * 64, wn = (wave >> 1) * 64;
    const int lm = lane & 15, quad = lane >> 4;
    const int sw = lm & 7;
    const int srow = t >> 3;
    const int scg0 = t & 7;
    const int sbase = (t & 192) * 8;

    floatx4 acc[4][4] = {};

    for (int k0 = 0; k0 < 1024; k0 += 64) {
#pragma unroll
        for (int p = 0; p < 4; ++p) {
            int row = p * 32 + srow;
            int cg = scg0 ^ (row & 7);
            int grow = m0 + row; if (grow >= NLBL) grow = NLBL - 1;
            gload_lds16(A + (size_t)grow * 1024 + k0 + cg * 8, As + p * 2048 + sbase);
        }
#pragma unroll
        for (int p = 0; p < 4; ++p) {
            int row = p * 32 + srow;
            int cg = scg0 ^ (row & 7);
            gload_lds16(Bt + (size_t)(n0 + row) * 1024 + k0 + cg * 8, Bs + p * 2048 + sbase);
        }
        __syncthreads();
#pragma unroll
        for (int k = 0; k < 64; k += 32) {
            bf16x8 af[4], bg[4];
            int ko = (((k >> 3) + quad) ^ sw) * 8;
#pragma unroll
            for (int mi = 0; mi < 4; ++mi)
                af[mi] = *(const bf16x8*)(As + (wm + mi * 16 + lm) * 64 + ko);
#pragma unroll
            for (int ni = 0; ni < 4; ++ni)
                bg[ni] = *(const bf16x8*)(Bs + (wn + ni * 16 + lm) * 64 + ko);
#pragma unroll
            for (int mi = 0; mi < 4; ++mi)
#pragma unroll
                for (int ni = 0; ni < 4; ++ni)
                    acc[mi][ni] = __builtin_amdgcn_mfma_f32_16x16x32_bf16(af[mi], bg[ni], acc[mi][ni], 0, 0, 0);
        }
        __syncthreads();
    }

    // acc -> Ls (bf16 hl tile), and stage hpb slice
#pragma unroll
    for (int mi = 0; mi < 4; ++mi)
#pragma unroll
        for (int r = 0; r < 4; ++r)
#pragma unroll
            for (int ni = 0; ni < 4; ++ni)
                Ls[(wm + mi * 16 + quad * 4 + r) * 136 + wn + ni * 16 + lm] =
                    (bf16)acc[mi][ni][r];
    {
        int dl = (t & 31) * 4;
        int b = t >> 5;                     // 0..7
        *(floatx4*)(hpbs + b * 128 + dl) =
            *(const floatx4*)(hpb + (size_t)b * DLAT + n0 + dl);
        *(floatx4*)(hpbs + (b + 8) * 128 + dl) =
            *(const floatx4*)(hpb + (size_t)(b + 8) * DLAT + n0 + dl);
    }
    __syncthreads();

    // read hl row-contiguous once, then 16 b passes of add+relu+bf16x8 stores
    const int g = t & 15;                   // d-granule (16B)
    const int r0 = t >> 4;                  // 0..15 base row
    bf16x8 hlv[8];
#pragma unroll
    for (int p = 0; p < 8; ++p)
        hlv[p] = *(const bf16x8*)(Ls + (p * 16 + r0) * 136 + g * 8);

    for (int b = 0; b < B_SEQ; ++b) {
        floatx4 h0 = *(const floatx4*)(hpbs + b * 128 + g * 8);
        floatx4 h4 = *(const floatx4*)(hpbs + b * 128 + g * 8 + 4);
        size_t rowbase = (size_t)b * NLBL * 1024;
#pragma unroll
        for (int p = 0; p < 8; ++p) {
            int n = m0 + p * 16 + r0;
            if (n >= NLBL) continue;
            bf16x8 o;
            o[0] = (bf16)fmaxf((float)hlv[p][0] + h0.x, 0.f);
            o[1] = (bf16)fmaxf((float)hlv[p][1] + h0.y, 0.f);
            o[2] = (bf16)fmaxf((float)hlv[p][2] + h0.z, 0.f);
            o[3] = (bf16)fmaxf((float)hlv[p][3] + h0.w, 0.f);
            o[4] = (bf16)fmaxf((float)hlv[p][4] + h4.x, 0.f);
            o[5] = (bf16)fmaxf((float)hlv[p][5] + h4.y, 0.f);
            o[6] = (bf16)fmaxf((float)hlv[p][6] + h4.z, 0.f);
            o[7] = (bf16)fmaxf((float)hlv[p][7] + h4.w, 0.f);
            *(bf16x8*)(h1 + rowbase + (size_t)n * 1024 + n0 + g * 8) = o;
        }
    }
}

// ============ K4: main GEMM h1 @ W2.T (32x32x16 MFMA) + fused relu/b2/W3 epilogue ============
// flat grid 5000, XCD-affinity mapping; staging identical to r5 (known good).
// Per wave: 64x64 tile as 2x2 blocks of 32x32. A/B frag: [row=lane&31][k=(lane>>5)*8+j].
// C/D (m74/m101-verified): col=lane&31, row=(reg&3)+8*(reg>>2)+4*(lane>>5).

__global__ __launch_bounds__(256)
void gemm_h2(const bf16* __restrict__ h1, const bf16* __restrict__ W2b,
             const float* __restrict__ b2, const float* __restrict__ W3,
             float* __restrict__ out) {
    __shared__ bf16 As[128 * 64];
    __shared__ bf16 Bs[128 * 64];
    const int t = threadIdx.x;
    int flat = blockIdx.x;
    int x = flat & 7;
    int s = flat >> 3;
    int mt, nt;
    if (s < 624) { mt = x * 78 + (s >> 3); nt = s & 7; }
    else         { mt = 624; nt = x; }
    const int m0 = mt * 128, n0 = nt * 128;

    const int wave = t >> 6, lane = t & 63;
    const int wm = (wave & 1) * 64, wn = (wave >> 1) * 64;
    const int l31 = lane & 31;
    const int half = lane >> 5;
    const int srow = t >> 3;
    const int scg0 = t & 7;
    const int sbase = (t & 192) * 8;

    floatx16 acc[2][2] = {};
    const bf16* Abase = h1 + (size_t)m0 * 1024;
    const bf16* Bbase = W2b + (size_t)n0 * 1024;

    for (int k0 = 0; k0 < 1024; k0 += 64) {
#pragma unroll
        for (int p = 0; p < 4; ++p) {
            int row = p * 32 + srow;
            int cg = scg0 ^ (row & 7);
            gload_lds16(Abase + (size_t)row * 1024 + k0 + cg * 8, As + p * 2048 + sbase);
        }
#pragma unroll
        for (int p = 0; p < 4; ++p) {
            int row = p * 32 + srow;
            int cg = scg0 ^ (row & 7);
            gload_lds16(Bbase + (size_t)row * 1024 + k0 + cg * 8, Bs + p * 2048 + sbase);
        }
        __syncthreads();
#pragma unroll
        for (int ks = 0; ks < 4; ++ks) {
            bf16x8 af[2], bg[2];
#pragma unroll
            for (int mi = 0; mi < 2; ++mi) {
                int row = wm + mi * 32 + l31;
                int sg = ((ks << 1) | half) ^ (row & 7);
                af[mi] = *(const bf16x8*)(As + row * 64 + sg * 8);
            }
#pragma unroll
            for (int ni = 0; ni < 2; ++ni) {
                int row = wn + ni * 32 + l31;
                int sg = ((ks << 1) | half) ^ (row & 7);
                bg[ni] = *(const bf16x8*)(Bs + row * 64 + sg * 8);
            }
#pragma unroll
            for (int mi = 0; mi < 2; ++mi)
#pragma unroll
                for (int ni = 0; ni < 2; ++ni)
                    acc[mi][ni] = __builtin_amdgcn_mfma_f32_32x32x16_bf16(af[mi], bg[ni], acc[mi][ni], 0, 0, 0);
        }
        __syncthreads();
    }

    float w3v[2], b2v[2];
#pragma unroll
    for (int ni = 0; ni < 2; ++ni) {
        int col = n0 + wn + ni * 32 + l31;
        w3v[ni] = W3[col];
        b2v[ni] = b2[col];
    }
#pragma unroll
    for (int mi = 0; mi < 2; ++mi) {
#pragma unroll
        for (int reg = 0; reg < 16; ++reg) {
            float sacc = fmaxf(acc[mi][0][reg] + b2v[0], 0.f) * w3v[0]
                       + fmaxf(acc[mi][1][reg] + b2v[1], 0.f) * w3v[1];
            sacc += __shfl_xor(sacc, 1, 64);
            sacc += __shfl_xor(sacc, 2, 64);
            sacc += __shfl_xor(sacc, 4, 64);
            sacc += __shfl_xor(sacc, 8, 64);
            sacc += __shfl_xor(sacc, 16, 64);
            if (l31 == 0) {
                int row = m0 + wm + mi * 32 + (reg & 3) + 8 * (reg >> 2) + 4 * half;
                atomicAdd(out + row, sacc);
            }
        }
    }
}

// ---------------- launch ----------------

extern "C" void kernel_launch(void* const* d_in, const int* in_sizes, int n_in,
                              void* d_out, int out_size, void* d_ws, size_t ws_size,
                              hipStream_t stream) {
    const float* seq   = (const float*)d_in[0];
    const float* label = (const float*)d_in[1];
    const float* Wp    = (const float*)d_in[2];
    const float* Wl    = (const float*)d_in[3];
    const float* W1    = (const float*)d_in[4];
    const float* b1    = (const float*)d_in[5];
    const float* W2    = (const float*)d_in[6];
    const float* b2    = (const float*)d_in[7];
    const float* W3    = (const float*)d_in[8];
    const float* b3    = (const float*)d_in[9];
    float* out = (float*)d_out;
    (void)n_in; (void)in_sizes; (void)out_size; (void)ws_size;

    size_t off = 0;
    auto alloc = [&](size_t bytes) {
        void* p = (char*)d_ws + off;
        off += (bytes + 255) & ~(size_t)255;
        return p;
    };
    bf16* label_b = (bf16*)alloc((size_t)NLBL * 1024 * 2);
    bf16* W2_b    = (bf16*)alloc((size_t)1024 * 1024 * 2);
    bf16* M_bf    = (bf16*)alloc((size_t)1024 * 1024 * 2);
    float* Pe     = (float*)alloc((size_t)B_SEQ * 1024 * 4);
    float* hpb    = (float*)alloc((size_t)B_SEQ * 1024 * 4);
    bf16* h1      = (bf16*)alloc((size_t)NROWS * 1024 * 2);

    prep_kernel<<<PSEG_END, 256, 0, stream>>>(label, label_b, W2, W2_b, W1, Wl,
                                              M_bf, seq, Wp, Pe, out, b3);
    hpb_kernel<<<256, 256, 0, stream>>>(Pe, W1, b1, hpb);
    hl_h1_kernel<<<dim3(8, 40), 256, 0, stream>>>(label_b, M_bf, hpb, h1);
    gemm_h2<<<5000, 256, 0, stream>>>(h1, W2_b, b2, W3, out);
}

// Round 9
// 336.270 us; speedup vs baseline: 1.1169x; 1.1169x over previous
//
#include <hip/hip_runtime.h>
#include <hip/hip_bf16.h>
#include <stdint.h>

typedef __bf16 bf16;
typedef __bf16 bf16x4 __attribute__((ext_vector_type(4)));
typedef __bf16 bf16x8 __attribute__((ext_vector_type(8)));
typedef float floatx4 __attribute__((ext_vector_type(4)));

#define B_SEQ 16
#define NLBL  5000
#define DLAT  1024
#define PDIM  1100
#define NROWS (B_SEQ * NLBL)   // 80000 = 625 * 128

// NOTE (R6): never use the builtin's immediate-offset arg — it mis-addresses.
// NOTE (R8): 32x32 MFMA frag reads 4-way bank-conflict under this LDS layout
// (8 slots, 128B row stride). 16x16 is the conflict-free shape here.
__device__ __forceinline__ void gload_lds16(const bf16* g, bf16* l) {
    __builtin_amdgcn_global_load_lds(
        (const __attribute__((address_space(1))) void*)g,
        (__attribute__((address_space(3))) void*)l, 16, 0, 0);
}

__device__ __forceinline__ bf16x8 cvt8(const float* s) {
    floatx4 a = *(const floatx4*)s;
    floatx4 b = *(const floatx4*)(s + 4);
    bf16x8 o;
    o[0] = (bf16)a.x; o[1] = (bf16)a.y; o[2] = (bf16)a.z; o[3] = (bf16)a.w;
    o[4] = (bf16)b.x; o[5] = (bf16)b.y; o[6] = (bf16)b.z; o[7] = (bf16)b.w;
    return o;
}

// ============ K1: prep ============
#define PSEG_M    256
#define PSEG_LAB  2756
#define PSEG_W2   3268
#define PSEG_PE   3524
#define PSEG_END  3837

__global__ __launch_bounds__(256)
void prep_kernel(const float* __restrict__ label, bf16* __restrict__ label_b,
                 const float* __restrict__ W2, bf16* __restrict__ W2_b,
                 const float* __restrict__ W1, const float* __restrict__ Wl,
                 bf16* __restrict__ M_bf,
                 const float* __restrict__ seq, const float* __restrict__ Wp,
                 float* __restrict__ Pe,
                 float* __restrict__ out, const float* __restrict__ b3) {
    __shared__ bf16 MAs[64 * 72];
    __shared__ bf16 MBs[64 * 72];
    const int blk = blockIdx.x;
    const int t = threadIdx.x;

    if (blk < PSEG_M) {                     // M-product, 64x64 tiles, 16x16 grid
        const int m0 = (blk >> 4) * 64;
        const int n0g = (blk & 15) * 64;
        const int wave = t >> 6, lane = t & 63;
        const int wm = (wave & 1) * 32, wn = (wave >> 1) * 32;
        const int lm = lane & 15, quad = lane >> 4;
        const int a_r = t >> 2, a_c = (t & 3) * 16;
        const int b_kr = t >> 4, b_l = (t & 15) * 4;
        floatx4 acc[2][2] = {};

        for (int k0 = 0; k0 < 1024; k0 += 64) {
            const float* ap = W1 + (size_t)(m0 + a_r) * 2048 + 1024 + k0 + a_c;
            *(bf16x8*)(MAs + a_r * 72 + a_c) = cvt8(ap);
            *(bf16x8*)(MAs + a_r * 72 + a_c + 8) = cvt8(ap + 8);
#pragma unroll
            for (int ps = 0; ps < 4; ++ps) {
                int kr = b_kr + ps * 16;
                floatx4 v = *(const floatx4*)(Wl + (size_t)(k0 + kr) * 1024 + n0g + b_l);
                MBs[(b_l + 0) * 72 + kr] = (bf16)v.x;
                MBs[(b_l + 1) * 72 + kr] = (bf16)v.y;
                MBs[(b_l + 2) * 72 + kr] = (bf16)v.z;
                MBs[(b_l + 3) * 72 + kr] = (bf16)v.w;
            }
            __syncthreads();
#pragma unroll
            for (int ks = 0; ks < 2; ++ks) {
                bf16x8 af[2], bg[2];
#pragma unroll
                for (int mi = 0; mi < 2; ++mi)
                    af[mi] = *(const bf16x8*)(MAs + (wm + mi * 16 + lm) * 72 + ks * 32 + quad * 8);
#pragma unroll
                for (int ni = 0; ni < 2; ++ni)
                    bg[ni] = *(const bf16x8*)(MBs + (wn + ni * 16 + lm) * 72 + ks * 32 + quad * 8);
#pragma unroll
                for (int mi = 0; mi < 2; ++mi)
#pragma unroll
                    for (int ni = 0; ni < 2; ++ni)
                        acc[mi][ni] = __builtin_amdgcn_mfma_f32_16x16x32_bf16(af[mi], bg[ni], acc[mi][ni], 0, 0, 0);
            }
            __syncthreads();
        }
#pragma unroll
        for (int mi = 0; mi < 2; ++mi)
#pragma unroll
            for (int r = 0; r < 4; ++r)
#pragma unroll
                for (int ni = 0; ni < 2; ++ni)
                    M_bf[(size_t)(m0 + wm + mi * 16 + quad * 4 + r) * 1024 + n0g + wn + ni * 16 + lm] =
                        (bf16)acc[mi][ni][r];
    } else if (blk < PSEG_LAB) {            // label convert
        int i = (blk - PSEG_M) * 256 + t;
        ((bf16x8*)label_b)[i] = cvt8(label + (size_t)i * 8);
    } else if (blk < PSEG_W2) {             // W2 convert
        int i = (blk - PSEG_LAB) * 256 + t;
        ((bf16x8*)W2_b)[i] = cvt8(W2 + (size_t)i * 8);
    } else if (blk < PSEG_PE) {             // Pe, wave per d
        int w = (blk - PSEG_W2) * 4 + (t >> 6);
        int l = t & 63;
        floatx4 wv[5];
#pragma unroll
        for (int k = 0; k < 5; ++k) {
            int g = l + 64 * k;
            wv[k] = (g < 275) ? *(const floatx4*)(Wp + (size_t)w * PDIM + g * 4)
                              : floatx4{0.f, 0.f, 0.f, 0.f};
        }
        for (int b = 0; b < B_SEQ; ++b) {
            float acc = 0.f;
#pragma unroll
            for (int k = 0; k < 5; ++k) {
                int g = l + 64 * k;
                if (g < 275) {
                    floatx4 sv = *(const floatx4*)(seq + (size_t)b * PDIM + g * 4);
                    acc += wv[k].x * sv.x + wv[k].y * sv.y + wv[k].z * sv.z + wv[k].w * sv.w;
                }
            }
#pragma unroll
            for (int off = 32; off; off >>= 1) acc += __shfl_xor(acc, off, 64);
            if (l == 0) Pe[b * DLAT + w] = acc;
        }
    } else {                                // out init
        int i = (blk - PSEG_PE) * 256 + t;
        if (i < NROWS) out[i] = b3[0];
    }
}

// ============ K2: hpb[b,o] = b1[o] + Pe[b,:].W1[o,0:1024]  (f32 exact) ============

__global__ __launch_bounds__(256)
void hpb_kernel(const float* __restrict__ Pe, const float* __restrict__ W1,
                const float* __restrict__ b1, float* __restrict__ hpb) {
    int w = blockIdx.x * 4 + (threadIdx.x >> 6);
    int l = threadIdx.x & 63;
    floatx4 wv[4];
#pragma unroll
    for (int k = 0; k < 4; ++k)
        wv[k] = *(const floatx4*)(W1 + (size_t)w * 2048 + (l + 64 * k) * 4);
    for (int b = 0; b < B_SEQ; ++b) {
        float acc = 0.f;
#pragma unroll
        for (int k = 0; k < 4; ++k) {
            floatx4 pv = *(const floatx4*)(Pe + (size_t)b * DLAT + (l + 64 * k) * 4);
            acc += wv[k].x * pv.x + wv[k].y * pv.y + wv[k].z * pv.z + wv[k].w * pv.w;
        }
#pragma unroll
        for (int off = 32; off; off >>= 1) acc += __shfl_xor(acc, off, 64);
        if (l == 0) hpb[b * DLAT + w] = acc + b1[w];
    }
}

// ============ K3: hl GEMM (label @ M.T) with coalesced h1 epilogue ============
// R9: 64-row n-tiles -> grid (8 d-tiles, 79 n-tiles) = 632 blocks (~2.5/CU)
// for flatter tail than 320 blocks @ 1.25/CU. Tile: 64 n-rows x 128 d-cols.
// h1[(b*5000+n), d] = bf16(relu(hpb[b,d] + hl[n,d])) for all 16 b.

__global__ __launch_bounds__(256)
void hl_h1_kernel(const bf16* __restrict__ A, const bf16* __restrict__ Bt,
                  const float* __restrict__ hpb, bf16* __restrict__ h1) {
    __shared__ __align__(16) char smem[25600];
    bf16* As = (bf16*)smem;                 // 64 x 64 = 8 KB (K-loop)
    bf16* Bs = (bf16*)(smem + 8192);        // 128 x 64 = 16 KB (K-loop)
    bf16* Ls = (bf16*)smem;                 // 64*136*2 = 17408 B (epilogue)
    float* hpbs = (float*)(smem + 17408);   // 16*128*4 = 8192 B (epilogue)

    const int t = threadIdx.x;
    const int d0 = blockIdx.x * 128;        // d-tile (8)
    const int n0 = blockIdx.y * 64;         // n-tile (79, last partial)
    const int wave = t >> 6, lane = t & 63;
    const int wm = (wave & 1) * 32;         // n offset within 64
    const int wn = (wave >> 1) * 64;        // d offset within 128
    const int lm = lane & 15, quad = lane >> 4;
    const int sw = lm & 7;
    const int srow = t >> 3;                // 0..31
    const int scg0 = t & 7;
    const int sbase = (t & 192) * 8;

    floatx4 acc[2][4] = {};

    for (int k0 = 0; k0 < 1024; k0 += 64) {
#pragma unroll
        for (int p = 0; p < 2; ++p) {       // A: 64 label rows
            int row = p * 32 + srow;
            int cg = scg0 ^ (row & 7);
            int grow = n0 + row; if (grow >= NLBL) grow = NLBL - 1;
            gload_lds16(A + (size_t)grow * 1024 + k0 + cg * 8, As + p * 2048 + sbase);
        }
#pragma unroll
        for (int p = 0; p < 4; ++p) {       // B: 128 M_bf rows (d)
            int row = p * 32 + srow;
            int cg = scg0 ^ (row & 7);
            gload_lds16(Bt + (size_t)(d0 + row) * 1024 + k0 + cg * 8, Bs + p * 2048 + sbase);
        }
        __syncthreads();
#pragma unroll
        for (int k = 0; k < 64; k += 32) {
            bf16x8 af[2], bg[4];
            int ko = (((k >> 3) + quad) ^ sw) * 8;
#pragma unroll
            for (int mi = 0; mi < 2; ++mi)
                af[mi] = *(const bf16x8*)(As + (wm + mi * 16 + lm) * 64 + ko);
#pragma unroll
            for (int ni = 0; ni < 4; ++ni)
                bg[ni] = *(const bf16x8*)(Bs + (wn + ni * 16 + lm) * 64 + ko);
#pragma unroll
            for (int mi = 0; mi < 2; ++mi)
#pragma unroll
                for (int ni = 0; ni < 4; ++ni)
                    acc[mi][ni] = __builtin_amdgcn_mfma_f32_16x16x32_bf16(af[mi], bg[ni], acc[mi][ni], 0, 0, 0);
        }
        __syncthreads();
    }

    // acc -> Ls (bf16 hl tile, rows = n 0..63, cols = d 0..127), stage hpb slice
#pragma unroll
    for (int mi = 0; mi < 2; ++mi)
#pragma unroll
        for (int r = 0; r < 4; ++r)
#pragma unroll
            for (int ni = 0; ni < 4; ++ni)
                Ls[(wm + mi * 16 + quad * 4 + r) * 136 + wn + ni * 16 + lm] =
                    (bf16)acc[mi][ni][r];
    {
        int dl = (t & 31) * 4;
        int b = t >> 5;                     // 0..7
        *(floatx4*)(hpbs + b * 128 + dl) =
            *(const floatx4*)(hpb + (size_t)b * DLAT + d0 + dl);
        *(floatx4*)(hpbs + (b + 8) * 128 + dl) =
            *(const floatx4*)(hpb + (size_t)(b + 8) * DLAT + d0 + dl);
    }
    __syncthreads();

    // read hl row-contiguous once, then 16 b passes of add+relu+bf16x8 stores
    const int g = t & 15;                   // d-granule (16B)
    const int r0 = t >> 4;                  // 0..15 base row
    bf16x8 hlv[4];
#pragma unroll
    for (int p = 0; p < 4; ++p)
        hlv[p] = *(const bf16x8*)(Ls + (p * 16 + r0) * 136 + g * 8);

    for (int b = 0; b < B_SEQ; ++b) {
        floatx4 h0 = *(const floatx4*)(hpbs + b * 128 + g * 8);
        floatx4 h4 = *(const floatx4*)(hpbs + b * 128 + g * 8 + 4);
        size_t rowbase = (size_t)b * NLBL * 1024;
#pragma unroll
        for (int p = 0; p < 4; ++p) {
            int n = n0 + p * 16 + r0;
            if (n >= NLBL) continue;
            bf16x8 o;
            o[0] = (bf16)fmaxf((float)hlv[p][0] + h0.x, 0.f);
            o[1] = (bf16)fmaxf((float)hlv[p][1] + h0.y, 0.f);
            o[2] = (bf16)fmaxf((float)hlv[p][2] + h0.z, 0.f);
            o[3] = (bf16)fmaxf((float)hlv[p][3] + h0.w, 0.f);
            o[4] = (bf16)fmaxf((float)hlv[p][4] + h4.x, 0.f);
            o[5] = (bf16)fmaxf((float)hlv[p][5] + h4.y, 0.f);
            o[6] = (bf16)fmaxf((float)hlv[p][6] + h4.z, 0.f);
            o[7] = (bf16)fmaxf((float)hlv[p][7] + h4.w, 0.f);
            *(bf16x8*)(h1 + rowbase + (size_t)n * 1024 + d0 + g * 8) = o;
        }
    }
}

// ============ K4: main GEMM h1 @ W2.T (16x16x32, r5 form) + fused epilogue ============
// flat grid 5000, XCD-affinity: block->XCD = id%8, 78 contiguous m-tiles/XCD,
// n fastest. 3x measured at 199.5 us / 872 TF / 0 bank conflicts.

__global__ __launch_bounds__(256)
void gemm_h2(const bf16* __restrict__ h1, const bf16* __restrict__ W2b,
             const float* __restrict__ b2, const float* __restrict__ W3,
             float* __restrict__ out) {
    __shared__ bf16 As[128 * 64];
    __shared__ bf16 Bs[128 * 64];
    const int t = threadIdx.x;
    int flat = blockIdx.x;
    int x = flat & 7;
    int s = flat >> 3;
    int mt, nt;
    if (s < 624) { mt = x * 78 + (s >> 3); nt = s & 7; }
    else         { mt = 624; nt = x; }
    const int m0 = mt * 128, n0 = nt * 128;

    const int wave = t >> 6, lane = t & 63;
    const int wm = (wave & 1) * 64, wn = (wave >> 1) * 64;
    const int lm = lane & 15, quad = lane >> 4;
    const int sw = lm & 7;
    const int srow = t >> 3;
    const int scg0 = t & 7;
    const int sbase = (t & 192) * 8;

    floatx4 acc[4][4] = {};
    const bf16* Abase = h1 + (size_t)m0 * 1024;
    const bf16* Bbase = W2b + (size_t)n0 * 1024;

    for (int k0 = 0; k0 < 1024; k0 += 64) {
#pragma unroll
        for (int p = 0; p < 4; ++p) {
            int row = p * 32 + srow;
            int cg = scg0 ^ (row & 7);
            gload_lds16(Abase + (size_t)row * 1024 + k0 + cg * 8, As + p * 2048 + sbase);
        }
#pragma unroll
        for (int p = 0; p < 4; ++p) {
            int row = p * 32 + srow;
            int cg = scg0 ^ (row & 7);
            gload_lds16(Bbase + (size_t)row * 1024 + k0 + cg * 8, Bs + p * 2048 + sbase);
        }
        __syncthreads();
#pragma unroll
        for (int k = 0; k < 64; k += 32) {
            bf16x8 af[4], bg[4];
            int ko = (((k >> 3) + quad) ^ sw) * 8;
#pragma unroll
            for (int mi = 0; mi < 4; ++mi)
                af[mi] = *(const bf16x8*)(As + (wm + mi * 16 + lm) * 64 + ko);
#pragma unroll
            for (int ni = 0; ni < 4; ++ni)
                bg[ni] = *(const bf16x8*)(Bs + (wn + ni * 16 + lm) * 64 + ko);
#pragma unroll
            for (int mi = 0; mi < 4; ++mi)
#pragma unroll
                for (int ni = 0; ni < 4; ++ni)
                    acc[mi][ni] = __builtin_amdgcn_mfma_f32_16x16x32_bf16(af[mi], bg[ni], acc[mi][ni], 0, 0, 0);
        }
        __syncthreads();
    }

    float w3v[4], b2v[4];
#pragma unroll
    for (int ni = 0; ni < 4; ++ni) {
        int col = n0 + wn + ni * 16 + lm;
        w3v[ni] = W3[col];
        b2v[ni] = b2[col];
    }
#pragma unroll
    for (int mi = 0; mi < 4; ++mi) {
#pragma unroll
        for (int r = 0; r < 4; ++r) {
            float sacc = 0.f;
#pragma unroll
            for (int ni = 0; ni < 4; ++ni)
                sacc += fmaxf(acc[mi][ni][r] + b2v[ni], 0.f) * w3v[ni];
            sacc += __shfl_xor(sacc, 1, 64);
            sacc += __shfl_xor(sacc, 2, 64);
            sacc += __shfl_xor(sacc, 4, 64);
            sacc += __shfl_xor(sacc, 8, 64);
            if (lm == 0)
                atomicAdd(out + m0 + wm + mi * 16 + quad * 4 + r, sacc);
        }
    }
}

// ---------------- launch ----------------

extern "C" void kernel_launch(void* const* d_in, const int* in_sizes, int n_in,
                              void* d_out, int out_size, void* d_ws, size_t ws_size,
                              hipStream_t stream) {
    const float* seq   = (const float*)d_in[0];
    const float* label = (const float*)d_in[1];
    const float* Wp    = (const float*)d_in[2];
    const float* Wl    = (const float*)d_in[3];
    const float* W1    = (const float*)d_in[4];
    const float* b1    = (const float*)d_in[5];
    const float* W2    = (const float*)d_in[6];
    const float* b2    = (const float*)d_in[7];
    const float* W3    = (const float*)d_in[8];
    const float* b3    = (const float*)d_in[9];
    float* out = (float*)d_out;
    (void)n_in; (void)in_sizes; (void)out_size; (void)ws_size;

    size_t off = 0;
    auto alloc = [&](size_t bytes) {
        void* p = (char*)d_ws + off;
        off += (bytes + 255) & ~(size_t)255;
        return p;
    };
    bf16* label_b = (bf16*)alloc((size_t)NLBL * 1024 * 2);
    bf16* W2_b    = (bf16*)alloc((size_t)1024 * 1024 * 2);
    bf16* M_bf    = (bf16*)alloc((size_t)1024 * 1024 * 2);
    float* Pe     = (float*)alloc((size_t)B_SEQ * 1024 * 4);
    float* hpb    = (float*)alloc((size_t)B_SEQ * 1024 * 4);
    bf16* h1      = (bf16*)alloc((size_t)NROWS * 1024 * 2);

    prep_kernel<<<PSEG_END, 256, 0, stream>>>(label, label_b, W2, W2_b, W1, Wl,
                                              M_bf, seq, Wp, Pe, out, b3);
    hpb_kernel<<<256, 256, 0, stream>>>(Pe, W1, b1, hpb);
    hl_h1_kernel<<<dim3(8, 79), 256, 0, stream>>>(label_b, M_bf, hpb, h1);
    gemm_h2<<<5000, 256, 0, stream>>>(h1, W2_b, b2, W3, out);
}